// Round 6
// baseline (567.771 us; speedup 1.0000x reference)
//
#include <hip/hip_runtime.h>
#include <stdint.h>

typedef __bf16 bf16_t;
typedef bf16_t bf16x8 __attribute__((ext_vector_type(8)));
typedef float f32x16 __attribute__((ext_vector_type(16)));

#define D_DIM 4096   // K
#define O_DIM 4096   // N
#define M_DIM 16384  // M
#define THRESH 0.05f

// ---------- helpers ----------

__device__ __forceinline__ void gld16(const void* g, void* l) {
  __builtin_amdgcn_global_load_lds(
      (const __attribute__((address_space(1))) uint32_t*)(uintptr_t)g,
      (__attribute__((address_space(3))) uint32_t*)(uint32_t)(uintptr_t)l,
      16, 0, 0);
}

__device__ __forceinline__ unsigned short f2bf(float f) {  // RNE f32->bf16
  uint32_t u = __float_as_uint(f);
  u += 0x7FFFu + ((u >> 16) & 1u);
  return (unsigned short)(u >> 16);
}

__device__ __forceinline__ unsigned short tern(float v) {  // bf16 bits of {-1,0,+1}
  return (__builtin_fabsf(v) < THRESH) ? (unsigned short)0
         : (v > 0.f ? (unsigned short)0x3F80 : (unsigned short)0xBF80);
}

// ---------- pre-pass kernels (verified rounds 1-4) ----------

__global__ void k_scale_part(const float* __restrict__ w, float* __restrict__ part) {
  const int cg = blockIdx.x & 63;
  const int dz = blockIdx.x >> 6;
  const int tx = threadIdx.x & 63;
  const int ty = threadIdx.x >> 6;
  const int o = cg * 64 + tx;
  float s = 0.f;
  const float* p = w + (size_t)(dz * 512 + ty) * O_DIM + o;
  for (int i = 0; i < 128; ++i) {
    s += __builtin_fabsf(*p);
    p += 4 * O_DIM;
  }
  __shared__ float red[4][64];
  red[ty][tx] = s;
  __syncthreads();
  if (ty == 0) part[dz * O_DIM + o] = (red[0][tx] + red[1][tx]) + (red[2][tx] + red[3][tx]);
}

__global__ void k_scale_fin(const float* __restrict__ part, float* __restrict__ scale) {
  const int o = blockIdx.x * 256 + threadIdx.x;
  float s = 0.f;
#pragma unroll
  for (int z = 0; z < 8; ++z) s += part[z * O_DIM + o];
  scale[o] = s * (1.0f / 4096.0f);
}

__global__ void k_tern_t(const float* __restrict__ w, unsigned short* __restrict__ bt) {
  __shared__ __align__(16) unsigned short tile[64][68];
  const int ot = blockIdx.x & 63;
  const int dt = blockIdx.x >> 6;
  const int o0 = ot * 64, d0 = dt * 64;
  const int tx = threadIdx.x & 15, ty = threadIdx.x >> 4;
#pragma unroll
  for (int j = 0; j < 4; ++j) {
    const int r = ty + 16 * j;
    const float4 v = *(const float4*)&w[(size_t)(d0 + r) * O_DIM + o0 + tx * 4];
    ushort4 u;
    u.x = tern(v.x); u.y = tern(v.y); u.z = tern(v.z); u.w = tern(v.w);
    *(ushort4*)&tile[r][tx * 4] = u;
  }
  __syncthreads();
#pragma unroll
  for (int j = 0; j < 4; ++j) {
    const int orow = ty + 16 * j;
    ushort4 u;
    u.x = tile[tx * 4 + 0][orow];
    u.y = tile[tx * 4 + 1][orow];
    u.z = tile[tx * 4 + 2][orow];
    u.w = tile[tx * 4 + 3][orow];
    *(ushort4*)&bt[(size_t)(o0 + orow) * D_DIM + d0 + tx * 4] = u;
  }
}

__global__ void k_cvt(const float* __restrict__ x, unsigned short* __restrict__ xb) {
  const size_t i = ((size_t)blockIdx.x * 256 + threadIdx.x) * 8;
  const float4 a = *(const float4*)&x[i];
  const float4 b = *(const float4*)&x[i + 4];
  uint4 o;
  o.x = (uint32_t)f2bf(a.x) | ((uint32_t)f2bf(a.y) << 16);
  o.y = (uint32_t)f2bf(a.z) | ((uint32_t)f2bf(a.w) << 16);
  o.z = (uint32_t)f2bf(b.x) | ((uint32_t)f2bf(b.y) << 16);
  o.w = (uint32_t)f2bf(b.z) | ((uint32_t)f2bf(b.w) << 16);
  *(uint4*)&xb[i] = o;
}

// ---------- 256x256 GEMM, 32x32x16 MFMA, round-4 hazard-safe calendar ----------
// C[m][n] = (sum_k A[m][k]*Bt[n][k]) * scale[n] + bias[n]
// BM=BN=256, BK=64, 512 thr = 8 waves (2Mx4N), per-wave C = 128x64 = 4x2 of 32x32.
// LDS 128KB, measured-zero-conflict image (r2/r4): buf d, half h: granule (row,g)
// at byte row*128 + ((g^(row&7))<<4); staged via pre-swizzled GLOBAL addr.
// Frag (ks): lane reads row=base+(l&31), granule g=2ks+(l>>5): 8 lanes/16B slot
// = 2/bank (free). B of tile T+1 read ALL at T's p3 into parity regs (r4 rule).
// Calendar per tile T (buf d), stages target tile T+2 into buf d:
//   p0: read aq[0],aq[1](T) | stage B0 | lgkm(4) | MFMA ks0
//   p1: read aq[2],aq[3](T) | stage B1 | lgkm(8) | MFMA ks1
//   p2:                     | stage A0 | lgkm(4) | MFMA ks2 | vmcnt(6)
//   p3: read bq(T+1) all    | stage A1 | lgkm(8) | MFMA ks3
// Region-overwrite safety: every stage >=1 barrier after that region's last read.
// vmcnt(6)@p2 ledger: newest 6 = T's B0,B1,A0 -> tile T+1 fully staged.

#define BAR() __builtin_amdgcn_s_barrier()
#define SB0() __builtin_amdgcn_sched_barrier(0)
#define LGKM(n) asm volatile("s_waitcnt lgkmcnt(" #n ")" ::: "memory")
#define VMW(n) asm volatile("s_waitcnt vmcnt(" #n ")" ::: "memory")

#define STAGE_A(d, h, kv)                                                    \
  do {                                                                       \
    gld16(pA##h##_0 + (kv)*64, smem + (d)*32768 + (h)*16384 + t * 16);       \
    gld16(pA##h##_1 + (kv)*64,                                               \
          smem + (d)*32768 + (h)*16384 + 8192 + t * 16);                     \
  } while (0)
#define STAGE_B(d, h, kv)                                                    \
  do {                                                                       \
    gld16(pB##h##_0 + (kv)*64,                                               \
          smem + 65536 + (d)*32768 + (h)*16384 + t * 16);                    \
    gld16(pB##h##_1 + (kv)*64,                                               \
          smem + 65536 + (d)*32768 + (h)*16384 + 8192 + t * 16);             \
  } while (0)

#define RA(d, ks)                                                  \
  do {                                                             \
    const char* p_ = smem + (d)*32768 + aBase0 + sl##ks;           \
    aq[ks][0] = *(const bf16x8*)(p_);                              \
    aq[ks][1] = *(const bf16x8*)(p_ + 4096);                       \
    aq[ks][2] = *(const bf16x8*)(p_ + 8192);                       \
    aq[ks][3] = *(const bf16x8*)(p_ + 12288);                      \
  } while (0)
#define RB1(d, pp, ks)                                             \
  do {                                                             \
    const char* p_ = smem + (d)*32768 + bBase0 + sl##ks;           \
    bq[pp][ks][0] = *(const bf16x8*)(p_);                          \
    bq[pp][ks][1] = *(const bf16x8*)(p_ + 4096);                   \
  } while (0)
#define RB_ALL(d, pp)                                              \
  do {                                                             \
    RB1(d, pp, 0); RB1(d, pp, 1); RB1(d, pp, 2); RB1(d, pp, 3);    \
  } while (0)

#define MM(ks, pp)                                                            \
  do {                                                                        \
    __builtin_amdgcn_s_setprio(1);                                            \
    _Pragma("unroll") for (int m = 0; m < 4; ++m)                             \
    _Pragma("unroll") for (int n = 0; n < 2; ++n)                             \
        acc[m][n] = __builtin_amdgcn_mfma_f32_32x32x16_bf16(                  \
            aq[ks][m], bq[pp][ks][n], acc[m][n], 0, 0, 0);                    \
    __builtin_amdgcn_s_setprio(0);                                            \
  } while (0)

#define TILE(d, pp, kv)                                                  \
  do {                                                                   \
    RA(d, 0); RA(d, 1); STAGE_B(d, 0, kv);                               \
    BAR(); LGKM(4); SB0(); MM(0, pp); BAR();                             \
    RA(d, 2); RA(d, 3); STAGE_B(d, 1, kv);                               \
    BAR(); LGKM(8); SB0(); MM(1, pp); BAR();                             \
    STAGE_A(d, 0, kv);                                                   \
    BAR(); LGKM(4); SB0(); MM(2, pp); VMW(6); BAR();                     \
    RB_ALL((d) ^ 1, (pp) ^ 1); STAGE_A(d, 1, kv);                        \
    BAR(); LGKM(8); SB0(); MM(3, pp); BAR();                             \
  } while (0)

__global__ __launch_bounds__(512, 2) void k_gemm8(
    const unsigned short* __restrict__ A,   // [M][K] bf16 bits
    const unsigned short* __restrict__ B,   // [N][K] bf16 bits (ternary)
    const float* __restrict__ scale, const float* __restrict__ bias,
    float* __restrict__ C) {
  __shared__ __align__(16) char smem[131072];

  const int bid = blockIdx.x;
  const int wg = (bid & 7) * 128 + (bid >> 3);  // XCD swizzle, 1024%8==0
  const int mb = wg >> 4, nb = wg & 15;         // 64 x 16 blocks
  const int mBase = mb * 256, nBase = nb * 256;

  const int t = threadIdx.x;
  const int lane = t & 63, wid = t >> 6;
  const int wr = wid >> 2, wc = wid & 3;  // 2 x 4 waves
  const int l31 = lane & 31, lhi = lane >> 5;

  // per-lane read bases and per-ks slot offsets (zero-conflict image)
  const int aBase0 = (wr * 128 + l31) * 128;
  const int bBase0 = 65536 + (wc * 64 + l31) * 128;
  const int r7 = l31 & 7;
  const int sl0 = ((0 + lhi) ^ r7) << 4;
  const int sl1 = ((2 + lhi) ^ r7) << 4;
  const int sl2 = ((4 + lhi) ^ r7) << 4;
  const int sl3 = ((6 + lhi) ^ r7) << 4;

  // staging: thread t stages granules q0=t, q1=512+t of each 16KB half-tile
  const int q1 = 512 + t;
  const int sr0 = t >> 3, sg0 = (t & 7) ^ (sr0 & 7);
  const int sr1 = q1 >> 3, sg1 = (q1 & 7) ^ (sr1 & 7);

  const unsigned short* pA0_0 = A + (size_t)(mBase + sr0) * D_DIM + sg0 * 8;
  const unsigned short* pA0_1 = A + (size_t)(mBase + sr1) * D_DIM + sg1 * 8;
  const unsigned short* pA1_0 = A + (size_t)(mBase + 128 + sr0) * D_DIM + sg0 * 8;
  const unsigned short* pA1_1 = A + (size_t)(mBase + 128 + sr1) * D_DIM + sg1 * 8;
  const unsigned short* pB0_0 = B + (size_t)(nBase + sr0) * D_DIM + sg0 * 8;
  const unsigned short* pB0_1 = B + (size_t)(nBase + sr1) * D_DIM + sg1 * 8;
  const unsigned short* pB1_0 = B + (size_t)(nBase + 128 + sr0) * D_DIM + sg0 * 8;
  const unsigned short* pB1_1 = B + (size_t)(nBase + 128 + sr1) * D_DIM + sg1 * 8;

  f32x16 acc[4][2] = {};
  bf16x8 aq[4][4];     // [ks][m] — tile currently computing
  bf16x8 bq[2][4][2];  // [parity][ks][n] — B read one tile ahead

  // prologue: tile0 -> buf0, tile1 -> buf1 (16 gld); then pre-read bq(tile0)
  STAGE_B(0, 0, 0); STAGE_B(0, 1, 0); STAGE_A(0, 0, 0); STAGE_A(0, 1, 0);
  STAGE_B(1, 0, 1); STAGE_B(1, 1, 1); STAGE_A(1, 0, 1); STAGE_A(1, 1, 1);
  VMW(8);  // tile0's 8 ops landed
  BAR();
  RB_ALL(0, 0);
  LGKM(0);  // bq(tile0) in regs before any later overwrite can land
  BAR();

  for (int T = 0; T < 64; T += 2) {
    TILE(0, 0, (T + 2) & 63);  // &63: tiles 62/63 stage dummy wrap (never read)
    TILE(1, 1, (T + 3) & 63);
  }
  VMW(0);  // drain dummy stages

  // epilogue: 32x32 C/D mapping col=lane&31, row=(r&3)+8*(r>>2)+4*(lane>>5) (verified r3)
#pragma unroll
  for (int n = 0; n < 2; ++n) {
    const int gc = nBase + wc * 64 + n * 32 + l31;
    const float sc = scale[gc];
    const float bb = bias[gc];
#pragma unroll
    for (int m = 0; m < 4; ++m) {
      const int grb = mBase + wr * 128 + m * 32 + 4 * lhi;
#pragma unroll
      for (int r = 0; r < 16; ++r) {
        const int grow = grb + (r & 3) + 8 * (r >> 2);
        C[(size_t)grow * O_DIM + gc] = acc[m][n][r] * sc + bb;
      }
    }
  }
}

// ---------- launch ----------

extern "C" void kernel_launch(void* const* d_in, const int* in_sizes, int n_in,
                              void* d_out, int out_size, void* d_ws, size_t ws_size,
                              hipStream_t stream) {
  const float* x = (const float*)d_in[0];
  const float* w = (const float*)d_in[1];
  const float* bias = (const float*)d_in[2];
  float* out = (float*)d_out;

  const size_t XB_OFF = 0;
  const size_t BT_OFF = (size_t)M_DIM * D_DIM * 2;
  const size_t PART_OFF = BT_OFF + (size_t)O_DIM * D_DIM * 2;
  const size_t SCALE_OFF = PART_OFF + 8 * O_DIM * 4;
  const size_t NEED = SCALE_OFF + O_DIM * 4;
  if (ws_size < NEED) return;

  char* ws = (char*)d_ws;
  unsigned short* xb = (unsigned short*)(ws + XB_OFF);
  unsigned short* bt = (unsigned short*)(ws + BT_OFF);
  float* part = (float*)(ws + PART_OFF);
  float* scale = (float*)(ws + SCALE_OFF);

  k_scale_part<<<512, 256, 0, stream>>>(w, part);
  k_scale_fin<<<16, 256, 0, stream>>>(part, scale);
  k_tern_t<<<64 * 64, 256, 0, stream>>>(w, bt);
  k_cvt<<<(M_DIM * (D_DIM / 8)) / 256, 256, 0, stream>>>(x, xb);
  k_gemm8<<<1024, 512, 0, stream>>>(xb, bt, scale, bias, out);
}